// Round 1
// baseline (80.240 us; speedup 1.0000x reference)
//
#include <hip/hip_runtime.h>

// ConvCNP fused kernel for MI355X (gfx950).
// Shapes fixed by the reference: B=4, N=2048, M=8192, C=2 (density+1 conv ch), COUT=64.
#define NB    4
#define NN    2048
#define NM    8192
#define NCOUT 64

__device__ __forceinline__ float fexp2(float x) {
#if defined(__has_builtin)
#if __has_builtin(__builtin_amdgcn_exp2f)
    return __builtin_amdgcn_exp2f(x);   // v_exp_f32: 2^x
#else
    return exp2f(x);
#endif
#else
    return exp2f(x);
#endif
}

// block = 256 threads (4 waves). Each wave reduces over all N for TWO target
// points m; block covers 8 m. grid.x = NB * NM/8 = 4096.
// LDS: (x_n, y_n) interleaved float2 -> 16 KB -> 8 blocks/CU (full 32 waves/CU).
__global__ __launch_bounds__(256) void convcnp_kernel(
    const float* __restrict__ ci,    // context_in  (B,N,1)
    const float* __restrict__ co,    // context_out (B,N,1)
    const float* __restrict__ ti,    // target_in   (B,M,1)
    const float* __restrict__ sigma, // (2,)
    const float* __restrict__ W,     // (64,2) row-major
    const float* __restrict__ bias,  // (64,)
    float* __restrict__ out)         // (B,M,64)
{
    __shared__ float2 sxy[NN];
    const int tid   = threadIdx.x;
    const int bidx  = blockIdx.x;
    const int b     = bidx >> 10;           // 1024 blocks per batch
    const int mbase = (bidx & 1023) * 8;

    // Cooperative stage of this batch's context points into LDS (float4 loads).
    const float4* ci4 = (const float4*)(ci + (size_t)b * NN);
    const float4* co4 = (const float4*)(co + (size_t)b * NN);
    #pragma unroll
    for (int i = tid; i < NN / 4; i += 256) {
        float4 x = ci4[i];
        float4 y = co4[i];
        sxy[4 * i + 0] = make_float2(x.x, y.x);
        sxy[4 * i + 1] = make_float2(x.y, y.y);
        sxy[4 * i + 2] = make_float2(x.z, y.z);
        sxy[4 * i + 3] = make_float2(x.w, y.w);
    }

    // weights_c = exp(-0.5*d/exp(2*sigma_c)) = exp2(c_c * d)
    const float LOG2E = 1.4426950408889634f;
    const float c0 = -0.5f * __expf(-2.0f * sigma[0]) * LOG2E;
    const float c1 = -0.5f * __expf(-2.0f * sigma[1]) * LOG2E;
    __syncthreads();

    const int wave = tid >> 6;
    const int lane = tid & 63;
    const int m0 = mbase + wave * 2;
    const int m1 = m0 + 1;
    const float t0 = ti[(size_t)b * NM + m0];
    const float t1 = ti[(size_t)b * NM + m1];

    float a00 = 0.f, a01 = 0.f;  // m0: density, conv
    float a10 = 0.f, a11 = 0.f;  // m1: density, conv

    if (c0 == c1) {
        // one exp serves both channels (sigma[0]==sigma[1], the actual case)
        #pragma unroll 4
        for (int n = lane; n < NN; n += 64) {
            float2 xy = sxy[n];
            float d0 = xy.x - t0; d0 *= d0;
            float d1 = xy.x - t1; d1 *= d1;
            float w0 = fexp2(c0 * d0);
            float w1 = fexp2(c0 * d1);
            a00 += w0; a01 = fmaf(w0, xy.y, a01);
            a10 += w1; a11 = fmaf(w1, xy.y, a11);
        }
    } else {
        #pragma unroll 2
        for (int n = lane; n < NN; n += 64) {
            float2 xy = sxy[n];
            float d0 = xy.x - t0; d0 *= d0;
            float d1 = xy.x - t1; d1 *= d1;
            float w0a = fexp2(c0 * d0), w0b = fexp2(c1 * d0);
            float w1a = fexp2(c0 * d1), w1b = fexp2(c1 * d1);
            a00 += w0a; a01 = fmaf(w0b, xy.y, a01);
            a10 += w1a; a11 = fmaf(w1b, xy.y, a11);
        }
    }

    // 64-lane butterfly reduction (all lanes end with the full sums).
    #pragma unroll
    for (int off = 32; off > 0; off >>= 1) {
        a00 += __shfl_xor(a00, off, 64);
        a01 += __shfl_xor(a01, off, 64);
        a10 += __shfl_xor(a10, off, 64);
        a11 += __shfl_xor(a11, off, 64);
    }

    const float EPSF = 1e-8f;
    float o0a = a00, o1a = a01 / (a00 + EPSF);
    float o0b = a10, o1b = a11 / (a10 + EPSF);

    // Epilogue linear layer: lane j = output channel j. Coalesced 256B stores.
    float w0 = W[2 * lane], w1 = W[2 * lane + 1], bb = bias[lane];
    out[((size_t)b * NM + m0) * NCOUT + lane] = fmaf(o0a, w0, fmaf(o1a, w1, bb));
    out[((size_t)b * NM + m1) * NCOUT + lane] = fmaf(o0b, w0, fmaf(o1b, w1, bb));
}

extern "C" void kernel_launch(void* const* d_in, const int* in_sizes, int n_in,
                              void* d_out, int out_size, void* d_ws, size_t ws_size,
                              hipStream_t stream) {
    const float* ci    = (const float*)d_in[0];
    const float* co    = (const float*)d_in[1];
    const float* ti    = (const float*)d_in[2];
    const float* sigma = (const float*)d_in[3];
    const float* W     = (const float*)d_in[4];
    const float* bias  = (const float*)d_in[5];
    float* out = (float*)d_out;

    dim3 grid(NB * NM / 8);   // 4096 blocks
    dim3 block(256);
    hipLaunchKernelGGL(convcnp_kernel, grid, block, 0, stream,
                       ci, co, ti, sigma, W, bias, out);
}

// Round 2
// 78.260 us; speedup vs baseline: 1.0253x; 1.0253x over previous
//
#include <hip/hip_runtime.h>

// ConvCNP fused kernel for MI355X (gfx950).
// B=4, N=2048, M=8192, C=2 (density + 1 conv channel), COUT=64.
#define NB    4
#define NN    2048
#define NM    8192
#define NCOUT 64

typedef float v2f __attribute__((ext_vector_type(2)));

__device__ __forceinline__ float fexp2(float x) {
#if defined(__has_builtin)
#if __has_builtin(__builtin_amdgcn_exp2f)
    return __builtin_amdgcn_exp2f(x);   // v_exp_f32 (2^x); -x folds into src neg modifier
#else
    return exp2f(x);
#endif
#else
    return exp2f(x);
#endif
}

// block = 256 (4 waves). Each wave reduces over all N for FOUR target points m.
// Block covers 16 m. grid.x = NB*NM/16 = 2048 -> exactly 8 blocks/CU resident.
// LDS 16 KB -> occupancy capped by wave slots (8 blocks/CU), not LDS.
__global__ __launch_bounds__(256) void convcnp_kernel(
    const float* __restrict__ ci,    // context_in  (B,N,1)
    const float* __restrict__ co,    // context_out (B,N,1)
    const float* __restrict__ ti,    // target_in   (B,M,1)
    const float* __restrict__ sigma, // (2,)
    const float* __restrict__ W,     // (64,2) row-major
    const float* __restrict__ bias,  // (64,)
    float* __restrict__ out)         // (B,M,64)
{
    __shared__ float2 sxy[NN];
    const int tid   = threadIdx.x;
    const int b     = blockIdx.x >> 9;          // 512 blocks per batch
    const int mbase = (blockIdx.x & 511) * 16;

    // Stage this batch's (x_n, y_n) into LDS with float4 loads.
    const float4* ci4 = (const float4*)(ci + (size_t)b * NN);
    const float4* co4 = (const float4*)(co + (size_t)b * NN);
    #pragma unroll
    for (int i = tid; i < NN / 4; i += 256) {
        float4 x = ci4[i];
        float4 y = co4[i];
        sxy[4 * i + 0] = make_float2(x.x, y.x);
        sxy[4 * i + 1] = make_float2(x.y, y.y);
        sxy[4 * i + 2] = make_float2(x.z, y.z);
        sxy[4 * i + 3] = make_float2(x.w, y.w);
    }

    // w_c = exp(-0.5 d^2 / exp(2*sigma_c)) = exp2(-(r_c*d)^2), r_c = sqrt(0.5*log2e*exp(-2*sigma_c))
    const float LOG2E = 1.4426950408889634f;
    const float s0 = sigma[0], s1 = sigma[1];
    const float k0 = 0.5f * LOG2E * __expf(-2.0f * s0);
    const float k1 = 0.5f * LOG2E * __expf(-2.0f * s1);
    const float r0 = sqrtf(k0);
    const float r1 = sqrtf(k1);
    __syncthreads();

    const int wave = tid >> 6;
    const int lane = tid & 63;
    const int m0   = mbase + wave * 4;
    const float* tb = ti + (size_t)b * NM + m0;
    const float t0 = tb[0], t1 = tb[1], t2 = tb[2], t3 = tb[3];

    v2f den01 = {0.f, 0.f}, den23 = {0.f, 0.f};
    v2f cv01  = {0.f, 0.f}, cv23  = {0.f, 0.f};

    if (s0 == s1) {
        // sigma[0]==sigma[1] (the actual case): one exp serves both channels.
        const v2f r2    = {r0, r0};
        const v2f nrt01 = {-r0 * t0, -r0 * t1};
        const v2f nrt23 = {-r0 * t2, -r0 * t3};
        #pragma unroll 4
        for (int n = lane; n < NN; n += 64) {
            float2 xy = sxy[n];
            v2f x2 = {xy.x, xy.x};
            v2f y2 = {xy.y, xy.y};
            v2f e01 = x2 * r2 + nrt01;   // v_pk_fma_f32
            v2f e23 = x2 * r2 + nrt23;
            v2f f01 = e01 * e01;         // v_pk_mul_f32
            v2f f23 = e23 * e23;
            v2f w01, w23;
            w01.x = fexp2(-f01.x);       // v_exp_f32 with neg src modifier
            w01.y = fexp2(-f01.y);
            w23.x = fexp2(-f23.x);
            w23.y = fexp2(-f23.y);
            den01 += w01;                // v_pk_add_f32
            den23 += w23;
            cv01 = w01 * y2 + cv01;      // v_pk_fma_f32
            cv23 = w23 * y2 + cv23;
        }
    } else {
        // General path: density uses scale0, conv uses scale1.
        const float a0 = -r0 * t0, a1 = -r0 * t1, a2 = -r0 * t2, a3 = -r0 * t3;
        const float b0 = -r1 * t0, b1 = -r1 * t1, b2 = -r1 * t2, b3 = -r1 * t3;
        #pragma unroll 2
        for (int n = lane; n < NN; n += 64) {
            float2 xy = sxy[n];
            const float x = xy.x, y = xy.y;
            float ea0 = fmaf(r0, x, a0), ea1 = fmaf(r0, x, a1);
            float ea2 = fmaf(r0, x, a2), ea3 = fmaf(r0, x, a3);
            float eb0 = fmaf(r1, x, b0), eb1 = fmaf(r1, x, b1);
            float eb2 = fmaf(r1, x, b2), eb3 = fmaf(r1, x, b3);
            den01.x += fexp2(-ea0 * ea0); den01.y += fexp2(-ea1 * ea1);
            den23.x += fexp2(-ea2 * ea2); den23.y += fexp2(-ea3 * ea3);
            cv01.x = fmaf(fexp2(-eb0 * eb0), y, cv01.x);
            cv01.y = fmaf(fexp2(-eb1 * eb1), y, cv01.y);
            cv23.x = fmaf(fexp2(-eb2 * eb2), y, cv23.x);
            cv23.y = fmaf(fexp2(-eb3 * eb3), y, cv23.y);
        }
    }

    // 64-lane butterfly reduction; all lanes end with the full sums.
    #pragma unroll
    for (int off = 32; off > 0; off >>= 1) {
        den01.x += __shfl_xor(den01.x, off, 64);
        den01.y += __shfl_xor(den01.y, off, 64);
        den23.x += __shfl_xor(den23.x, off, 64);
        den23.y += __shfl_xor(den23.y, off, 64);
        cv01.x  += __shfl_xor(cv01.x,  off, 64);
        cv01.y  += __shfl_xor(cv01.y,  off, 64);
        cv23.x  += __shfl_xor(cv23.x,  off, 64);
        cv23.y  += __shfl_xor(cv23.y,  off, 64);
    }

    // Epilogue: out = [density, conv/(density+eps)] @ W^T + b. Lane j = channel j.
    const float EPSF = 1e-8f;
    const float den[4] = {den01.x, den01.y, den23.x, den23.y};
    const float cv[4]  = {cv01.x,  cv01.y,  cv23.x,  cv23.y};
    const float w0 = W[2 * lane], w1 = W[2 * lane + 1], bb = bias[lane];
    float* ob = out + ((size_t)b * NM + m0) * NCOUT + lane;
    #pragma unroll
    for (int k = 0; k < 4; ++k) {
        const float conv = cv[k] / (den[k] + EPSF);
        ob[(size_t)k * NCOUT] = fmaf(den[k], w0, fmaf(conv, w1, bb));
    }
}

extern "C" void kernel_launch(void* const* d_in, const int* in_sizes, int n_in,
                              void* d_out, int out_size, void* d_ws, size_t ws_size,
                              hipStream_t stream) {
    const float* ci    = (const float*)d_in[0];
    const float* co    = (const float*)d_in[1];
    const float* ti    = (const float*)d_in[2];
    const float* sigma = (const float*)d_in[3];
    const float* W     = (const float*)d_in[4];
    const float* bias  = (const float*)d_in[5];
    float* out = (float*)d_out;

    dim3 grid(NB * NM / 16);  // 2048 blocks
    dim3 block(256);
    hipLaunchKernelGGL(convcnp_kernel, grid, block, 0, stream,
                       ci, co, ti, sigma, W, bias, out);
}